// Round 8
// baseline (537.789 us; speedup 1.0000x reference)
//
#include <hip/hip_runtime.h>
#include <hip/hip_bf16.h>

#define CATS 17
#define SCALES 5
#define DIM 256
#define NSEG (CATS * SCALES)   // 85
#define TEMP 0.07f
#define NCHUNK 256             // row chunks; stream grid = (256, 2)
#define SCRATCH 32             // 4 waves x 8 scratch LDS rows (dedupe/pad sinks)
#define LROWS (NSEG + SCRATCH) // 117 LDS rows x 128 floats = 59,904 B

// ---------------------------------------------------------------------------
// Kernel 0: pack seg id = tgt*5+lvl into bytes (0xFF pad) + global histogram.
// ---------------------------------------------------------------------------
__global__ __launch_bounds__(256)
void pack_kernel(const int* __restrict__ tgt, const int* __restrict__ lvl,
                 unsigned char* __restrict__ seg8, int* __restrict__ gCnt,
                 int n, int npad4) {
    __shared__ int hist[NSEG];
    const int t = threadIdx.x;
    for (int i = t; i < NSEG; i += 256) hist[i] = 0;
    __syncthreads();

    const int i = blockIdx.x * 256 + t;
    if (i < npad4) {
        const int r = i * 4;
        int s0 = -1, s1 = -1, s2 = -1, s3 = -1;
        if (r + 3 < n) {
            const int4 tv = *reinterpret_cast<const int4*>(tgt + r);
            const int4 lv = *reinterpret_cast<const int4*>(lvl + r);
            s0 = tv.x * SCALES + lv.x; s1 = tv.y * SCALES + lv.y;
            s2 = tv.z * SCALES + lv.z; s3 = tv.w * SCALES + lv.w;
        } else {
            if (r + 0 < n) s0 = tgt[r + 0] * SCALES + lvl[r + 0];
            if (r + 1 < n) s1 = tgt[r + 1] * SCALES + lvl[r + 1];
            if (r + 2 < n) s2 = tgt[r + 2] * SCALES + lvl[r + 2];
            if (r + 3 < n) s3 = tgt[r + 3] * SCALES + lvl[r + 3];
        }
        uchar4 o;
        o.x = s0 >= 0 ? (unsigned char)s0 : 0xFF;
        o.y = s1 >= 0 ? (unsigned char)s1 : 0xFF;
        o.z = s2 >= 0 ? (unsigned char)s2 : 0xFF;
        o.w = s3 >= 0 ? (unsigned char)s3 : 0xFF;
        if (s0 >= 0) atomicAdd(&hist[s0], 1);
        if (s1 >= 0) atomicAdd(&hist[s1], 1);
        if (s2 >= 0) atomicAdd(&hist[s2], 1);
        if (s3 >= 0) atomicAdd(&hist[s3], 1);
        *reinterpret_cast<uchar4*>(seg8 + r) = o;
    }
    __syncthreads();
    for (int k = t; k < NSEG; k += 256)
        if (hist[k]) atomicAdd(&gCnt[k], hist[k]);
}

// ---------------------------------------------------------------------------
// Kernel 1: sequential stream + race-free private LDS accumulation.
// Block (chunk, h): 4 waves; wave w owns segs with seg&3==w; lane l owns
// dims (h*128 + 2l, +1). Per 64-row window: ballot, pop 8 uniform rows,
// 8 independent float2 loads, uniform in-batch seg dedupe (scratch-row
// redirect keeps all 8 LDS columns distinct), batched b64 read/add/write.
// No atomics, no syncs in the hot loop. Flush to per-block partials.
// ---------------------------------------------------------------------------
__global__ __launch_bounds__(256)
void stream_kernel(const float* __restrict__ feats,
                   const unsigned char* __restrict__ seg8,
                   float* __restrict__ partials, int RPB) {
    __shared__ float acc[LROWS * 128];
    const int t    = threadIdx.x;
    const int lane = t & 63;
    const int wv   = t >> 6;
    const int chunk = blockIdx.x;
    const int h     = blockIdx.y;
    const int base0 = chunk * RPB;

    float2* acc2 = reinterpret_cast<float2*>(acc);
    for (int i = t; i < LROWS * 64; i += 256) acc2[i] = make_float2(0.f, 0.f);
    __syncthreads();

    const float* fb = feats + h * 128 + lane * 2;
    const int nwin = RPB >> 6;

    int cur = seg8[base0 + lane];
    for (int win = 0; win < nwin; ++win) {
        const int base = base0 + (win << 6);
        const int nxt = (win + 1 < nwin) ? (int)seg8[base + 64 + lane] : 0xFF;

        unsigned long long m = __ballot((cur != 0xFF) & ((cur & 3) == wv));
        while (m) {
            int sg[8], rw[8]; float sc[8];
            #pragma unroll
            for (int u = 0; u < 8; ++u) {
                if (m) {
                    const int b = __ffsll((unsigned long long)m) - 1;
                    m &= m - 1;
                    rw[u] = base + b;
                    sg[u] = __shfl(cur, b);
                    sc[u] = 1.f;
                } else {
                    rw[u] = (u > 0) ? rw[u - 1] : base;
                    sg[u] = NSEG + wv * 8 + u;   // private scratch row
                    sc[u] = 0.f;
                }
            }
            float2 v[8];
            #pragma unroll
            for (int u = 0; u < 8; ++u)
                v[u] = *reinterpret_cast<const float2*>(fb + (size_t)rw[u] * DIM);
            #pragma unroll
            for (int u = 0; u < 8; ++u) { v[u].x *= sc[u]; v[u].y *= sc[u]; }

            // uniform in-batch dedupe: merge dup segs into first occurrence,
            // redirect the dup slot to its private scratch row.
            #pragma unroll
            for (int iu = 1; iu < 8; ++iu) {
                #pragma unroll
                for (int ju = 0; ju < iu; ++ju) {
                    if (sg[iu] == sg[ju]) {
                        v[ju].x += v[iu].x; v[ju].y += v[iu].y;
                        sg[iu] = NSEG + wv * 8 + iu;
                        break;
                    }
                }
            }
            int col[8];
            #pragma unroll
            for (int u = 0; u < 8; ++u) col[u] = sg[u] * 64 + lane;
            float2 tt[8];
            #pragma unroll
            for (int u = 0; u < 8; ++u) tt[u] = acc2[col[u]];   // batched reads
            #pragma unroll
            for (int u = 0; u < 8; ++u) { tt[u].x += v[u].x; tt[u].y += v[u].y; }
            #pragma unroll
            for (int u = 0; u < 8; ++u) acc2[col[u]] = tt[u];   // batched writes
        }
        cur = nxt;
    }
    __syncthreads();

    float2* dst = reinterpret_cast<float2*>(
        partials + (size_t)(h * NCHUNK + chunk) * (NSEG * 128));
    for (int i = t; i < NSEG * 64; i += 256) dst[i] = acc2[i];
}

// ---------------------------------------------------------------------------
// Kernel 2: reduce partials -> sums[85][256]. Block g, thread t: half h=t>>7.
// ---------------------------------------------------------------------------
__global__ __launch_bounds__(256)
void reduce_kernel(const float* __restrict__ partials,
                   float* __restrict__ sums) {
    const int g = blockIdx.x, t = threadIdx.x;
    const int h = t >> 7, d = t & 127;
    float s = 0.f;
    #pragma unroll 8
    for (int b = 0; b < NCHUNK; ++b)
        s += partials[(size_t)(h * NCHUNK + b) * (NSEG * 128) + g * 128 + d];
    sums[g * DIM + h * 128 + d] = s;
}

// ---------------------------------------------------------------------------
// Kernel 3: InfoNCE head + fused last-block finalize.
// ---------------------------------------------------------------------------
__global__ void infonce_kernel(const float* __restrict__ protos,  // [NSEG][DIM]
                               const float* __restrict__ sums,    // [NSEG][DIM]
                               const int* __restrict__ gCnt,      // [NSEG]
                               float* __restrict__ numAcc,
                               unsigned* __restrict__ doneCtr,
                               float* __restrict__ out) {
    const int cs   = blockIdx.x;
    const int s    = cs % SCALES;
    const int lane = threadIdx.x;

    const float4 p = *reinterpret_cast<const float4*>(
        protos + (size_t)cs * DIM + lane * 4);
    float ssq1 = p.x * p.x + p.y * p.y + p.z * p.z + p.w * p.w;
    #pragma unroll
    for (int off = 32; off > 0; off >>= 1) ssq1 += __shfl_down(ssq1, off);
    ssq1 = __shfl(ssq1, 0);

    float logits[CATS];
    for (int k = 0; k < CATS; ++k) {
        const int r2 = k * SCALES + s;
        const int cntv = gCnt[r2];
        float4 dv;
        if (cntv > 0) {
            const float4 sm = *reinterpret_cast<const float4*>(
                sums + (size_t)r2 * DIM + lane * 4);
            const float inv = 1.f / (float)cntv;
            dv = make_float4(sm.x * inv, sm.y * inv, sm.z * inv, sm.w * inv);
        } else {
            dv = make_float4(0.01f, 0.01f, 0.01f, 0.01f);
        }
        float ssq2 = dv.x * dv.x + dv.y * dv.y + dv.z * dv.z + dv.w * dv.w;
        float dot  = p.x * dv.x + p.y * dv.y + p.z * dv.z + p.w * dv.w;
        #pragma unroll
        for (int off = 32; off > 0; off >>= 1) {
            ssq2 += __shfl_down(ssq2, off);
            dot  += __shfl_down(dot, off);
        }
        const float lg = dot / (sqrtf(ssq2) * sqrtf(ssq1) * TEMP);
        logits[k] = __shfl(lg, 0);
    }

    if (lane == 0) {
        float mx = logits[0];
        #pragma unroll
        for (int k = 1; k < CATS; ++k) mx = fmaxf(mx, logits[k]);
        float sum = 0.f;
        #pragma unroll
        for (int k = 0; k < CATS; ++k) sum += expf(logits[k] - mx);
        const float lse     = mx + logf(sum);
        const int   label   = cs % CATS;
        const float per_row = lse - logits[label];
        unsafeAtomicAdd(numAcc, (gCnt[cs] > 0) ? per_row : 0.f);
        __threadfence();
        const unsigned done = atomicAdd(doneCtr, 1u);
        if (done == NSEG - 1) {
            __threadfence();
            float msum = 0.f;
            for (int i = 0; i < NSEG; ++i) msum += (gCnt[i] > 0) ? 1.f : 0.f;
            const float total = unsafeAtomicAdd(numAcc, 0.f);  // atomic read
            out[0] = total / fmaxf(msum, 1.f);
        }
    }
}

extern "C" void kernel_launch(void* const* d_in, const int* in_sizes, int n_in,
                              void* d_out, int out_size, void* d_ws, size_t ws_size,
                              hipStream_t stream) {
    const float* feats  = (const float*)d_in[0];   // [N][256] f32
    const int*   tgt    = (const int*)d_in[1];     // [N] int32
    const int*   lvl    = (const int*)d_in[2];     // [N] int32
    const float* protos = (const float*)d_in[3];   // [17][5][256] f32
    float* out = (float*)d_out;

    const int n = in_sizes[1];

    // rows per chunk, multiple of 64
    int RPB = (n + NCHUNK - 1) / NCHUNK;
    RPB = (RPB + 63) & ~63;
    const int npad  = NCHUNK * RPB;
    const int npad4 = npad / 4;

    // ws: numAcc@0 | doneCtr@4 | gCnt@8 | sums@512 | partials@87552 | seg8
    float*    numAcc   = (float*)d_ws;
    unsigned* doneCtr  = (unsigned*)((char*)d_ws + 4);
    int*      gCnt     = (int*)((char*)d_ws + 8);
    float*    sums     = (float*)((char*)d_ws + 512);
    float*    partials = (float*)((char*)d_ws + 512 + (size_t)NSEG * DIM * 4);
    const size_t partBytes = (size_t)2 * NCHUNK * NSEG * 128 * 4;
    unsigned char* seg8 = (unsigned char*)((char*)d_ws + 512
                          + (size_t)NSEG * DIM * 4 + partBytes);

    hipMemsetAsync(d_ws, 0, 8 + (size_t)NSEG * 4, stream);

    pack_kernel<<<(npad4 + 255) / 256, 256, 0, stream>>>(tgt, lvl, seg8, gCnt,
                                                         n, npad4);
    dim3 gs(NCHUNK, 2);
    stream_kernel<<<gs, 256, 0, stream>>>(feats, seg8, partials, RPB);
    reduce_kernel<<<NSEG, 256, 0, stream>>>(partials, sums);
    infonce_kernel<<<NSEG, 64, 0, stream>>>(protos, sums, gCnt, numAcc,
                                            doneCtr, out);
}

// Round 9
// 218.986 us; speedup vs baseline: 2.4558x; 2.4558x over previous
//
#include <hip/hip_runtime.h>
#include <hip/hip_bf16.h>

#define CATS 17
#define SCALES 5
#define DIM 256
#define NSEG (CATS * SCALES)   // 85
#define TEMP 0.07f
#define GPARTS 12              // gather blocks per segment: grid = 85*12 = 1020
#define CHUNK_ROWS 4096        // rows per build block (256 thr x 16)

// ---------------------------------------------------------------------------
// Kernel 0: build compact per-segment row-id lists.
// Per block: LDS histogram over 4096 rows, one global atomicAdd per (block,
// seg) reserves a slot range, LDS rank counters assign slots, scatter ids.
// ---------------------------------------------------------------------------
__global__ __launch_bounds__(256)
void build_kernel(const int* __restrict__ tgt, const int* __restrict__ lvl,
                  int* __restrict__ idx, int* __restrict__ gCnt,
                  int n, int idxStride) {
    __shared__ int hist[NSEG];
    __shared__ int baseb[NSEG];

    const int t  = threadIdx.x;
    const int r0 = blockIdx.x * CHUNK_ROWS;
    const int rbase = r0 + t * 16;

    for (int i = t; i < NSEG; i += 256) hist[i] = 0;
    __syncthreads();

    int segv[16];
    if (rbase + 16 <= n) {
        #pragma unroll
        for (int q = 0; q < 4; ++q) {
            const int4 tv = *reinterpret_cast<const int4*>(tgt + rbase + q * 4);
            const int4 lv = *reinterpret_cast<const int4*>(lvl + rbase + q * 4);
            segv[q * 4 + 0] = tv.x * SCALES + lv.x;
            segv[q * 4 + 1] = tv.y * SCALES + lv.y;
            segv[q * 4 + 2] = tv.z * SCALES + lv.z;
            segv[q * 4 + 3] = tv.w * SCALES + lv.w;
        }
    } else {
        #pragma unroll
        for (int k = 0; k < 16; ++k)
            segv[k] = (rbase + k < n)
                    ? tgt[rbase + k] * SCALES + lvl[rbase + k] : -1;
    }

    #pragma unroll
    for (int k = 0; k < 16; ++k)
        if (segv[k] >= 0) atomicAdd(&hist[segv[k]], 1);
    __syncthreads();

    for (int i = t; i < NSEG; i += 256)
        baseb[i] = atomicAdd(&gCnt[i], hist[i]);
    __syncthreads();
    for (int i = t; i < NSEG; i += 256) hist[i] = 0;   // reuse as rank ctrs
    __syncthreads();

    #pragma unroll
    for (int k = 0; k < 16; ++k) {
        const int s = segv[k];
        if (s >= 0) {
            const int rk = atomicAdd(&hist[s], 1);
            idx[(size_t)s * idxStride + baseb[s] + rk] = rbase + k;
        }
    }
}

// ---------------------------------------------------------------------------
// Kernel 1: pure streaming gather. Block (g,p): 256 threads = 4 waves.
// Each wave loads 64 row ids with one coalesced dword load, then streams the
// 1KB feature rows 8-deep (all loads real; ragged tails clamp the id and
// fma with scale 0). Register-only accumulation; tiny atomic flush.
// ---------------------------------------------------------------------------
__global__ __launch_bounds__(256)
void gather_kernel(const float* __restrict__ feats,
                   const int* __restrict__ idx,
                   const int* __restrict__ gCnt,
                   float* __restrict__ sums,     // [NSEG][DIM]
                   int idxStride) {
    const int bid  = blockIdx.x;
    const int g    = bid / GPARTS;
    const int p    = bid - g * GPARTS;
    const int lane = threadIdx.x & 63;
    const int wave = threadIdx.x >> 6;

    const int cnt   = gCnt[g];
    const int chunk = (cnt + GPARTS - 1) / GPARTS;
    const int e0    = p * chunk;
    const int e1    = min(e0 + chunk, cnt);
    const int* lst  = idx + (size_t)g * idxStride;

    float4 a0 = make_float4(0.f, 0.f, 0.f, 0.f), a1 = a0, a2 = a0, a3 = a0;
    float4 a4 = a0, a5 = a0, a6 = a0, a7 = a0;

    for (int e = e0 + wave * 64; e < e1; e += 256) {
        const int cntHere = min(64, e1 - e);
        const int ridv = lst[e + ((lane < cntHere) ? lane : 0)];

        if (cntHere == 64) {
            #pragma unroll
            for (int j0 = 0; j0 < 64; j0 += 8) {
                float4 v[8];
                #pragma unroll
                for (int u = 0; u < 8; ++u) {
                    const int sr = __shfl(ridv, j0 + u);
                    v[u] = *reinterpret_cast<const float4*>(
                        feats + (size_t)sr * DIM + lane * 4);
                }
                a0.x += v[0].x; a0.y += v[0].y; a0.z += v[0].z; a0.w += v[0].w;
                a1.x += v[1].x; a1.y += v[1].y; a1.z += v[1].z; a1.w += v[1].w;
                a2.x += v[2].x; a2.y += v[2].y; a2.z += v[2].z; a2.w += v[2].w;
                a3.x += v[3].x; a3.y += v[3].y; a3.z += v[3].z; a3.w += v[3].w;
                a4.x += v[4].x; a4.y += v[4].y; a4.z += v[4].z; a4.w += v[4].w;
                a5.x += v[5].x; a5.y += v[5].y; a5.z += v[5].z; a5.w += v[5].w;
                a6.x += v[6].x; a6.y += v[6].y; a6.z += v[6].z; a6.w += v[6].w;
                a7.x += v[7].x; a7.y += v[7].y; a7.z += v[7].z; a7.w += v[7].w;
            }
        } else {
            for (int j0 = 0; j0 < cntHere; j0 += 8) {
                float4 v[8]; float sc[8];
                #pragma unroll
                for (int u = 0; u < 8; ++u) {
                    const int jj = j0 + u;
                    const int jc = (jj < cntHere) ? jj : (cntHere - 1);
                    sc[u] = (jj < cntHere) ? 1.f : 0.f;
                    const int sr = __shfl(ridv, jc);
                    v[u] = *reinterpret_cast<const float4*>(
                        feats + (size_t)sr * DIM + lane * 4);
                }
                a0.x = fmaf(v[0].x, sc[0], a0.x); a0.y = fmaf(v[0].y, sc[0], a0.y);
                a0.z = fmaf(v[0].z, sc[0], a0.z); a0.w = fmaf(v[0].w, sc[0], a0.w);
                a1.x = fmaf(v[1].x, sc[1], a1.x); a1.y = fmaf(v[1].y, sc[1], a1.y);
                a1.z = fmaf(v[1].z, sc[1], a1.z); a1.w = fmaf(v[1].w, sc[1], a1.w);
                a2.x = fmaf(v[2].x, sc[2], a2.x); a2.y = fmaf(v[2].y, sc[2], a2.y);
                a2.z = fmaf(v[2].z, sc[2], a2.z); a2.w = fmaf(v[2].w, sc[2], a2.w);
                a3.x = fmaf(v[3].x, sc[3], a3.x); a3.y = fmaf(v[3].y, sc[3], a3.y);
                a3.z = fmaf(v[3].z, sc[3], a3.z); a3.w = fmaf(v[3].w, sc[3], a3.w);
                a4.x = fmaf(v[4].x, sc[4], a4.x); a4.y = fmaf(v[4].y, sc[4], a4.y);
                a4.z = fmaf(v[4].z, sc[4], a4.z); a4.w = fmaf(v[4].w, sc[4], a4.w);
                a5.x = fmaf(v[5].x, sc[5], a5.x); a5.y = fmaf(v[5].y, sc[5], a5.y);
                a5.z = fmaf(v[5].z, sc[5], a5.z); a5.w = fmaf(v[5].w, sc[5], a5.w);
                a6.x = fmaf(v[6].x, sc[6], a6.x); a6.y = fmaf(v[6].y, sc[6], a6.y);
                a6.z = fmaf(v[6].z, sc[6], a6.z); a6.w = fmaf(v[6].w, sc[6], a6.w);
                a7.x = fmaf(v[7].x, sc[7], a7.x); a7.y = fmaf(v[7].y, sc[7], a7.y);
                a7.z = fmaf(v[7].z, sc[7], a7.z); a7.w = fmaf(v[7].w, sc[7], a7.w);
            }
        }
    }

    a0.x += a1.x + a2.x + a3.x + a4.x + a5.x + a6.x + a7.x;
    a0.y += a1.y + a2.y + a3.y + a4.y + a5.y + a6.y + a7.y;
    a0.z += a1.z + a2.z + a3.z + a4.z + a5.z + a6.z + a7.z;
    a0.w += a1.w + a2.w + a3.w + a4.w + a5.w + a6.w + a7.w;

    float* dst = sums + (size_t)g * DIM + lane * 4;
    unsafeAtomicAdd(dst + 0, a0.x);
    unsafeAtomicAdd(dst + 1, a0.y);
    unsafeAtomicAdd(dst + 2, a0.z);
    unsafeAtomicAdd(dst + 3, a0.w);
}

// ---------------------------------------------------------------------------
// Kernel 2: InfoNCE head. One block (64 lanes) per output row cs = c*5+s.
// ---------------------------------------------------------------------------
__global__ void infonce_kernel(const float* __restrict__ protos,  // [NSEG][DIM]
                               const float* __restrict__ sums,    // [NSEG][DIM]
                               const int* __restrict__ gCnt,      // [NSEG]
                               float* __restrict__ numAcc) {
    const int cs   = blockIdx.x;        // c*SCALES + s
    const int s    = cs % SCALES;
    const int lane = threadIdx.x;       // 0..63, 4 dims each

    const float4 p = *reinterpret_cast<const float4*>(
        protos + (size_t)cs * DIM + lane * 4);
    float ssq1 = p.x * p.x + p.y * p.y + p.z * p.z + p.w * p.w;
    #pragma unroll
    for (int off = 32; off > 0; off >>= 1) ssq1 += __shfl_down(ssq1, off);
    ssq1 = __shfl(ssq1, 0);

    float logits[CATS];
    for (int k = 0; k < CATS; ++k) {
        const int r2 = k * SCALES + s;
        const int cntv = gCnt[r2];
        float4 dv;
        if (cntv > 0) {
            const float4 sm = *reinterpret_cast<const float4*>(
                sums + (size_t)r2 * DIM + lane * 4);
            const float inv = 1.f / (float)cntv;
            dv = make_float4(sm.x * inv, sm.y * inv, sm.z * inv, sm.w * inv);
        } else {
            dv = make_float4(0.01f, 0.01f, 0.01f, 0.01f);
        }
        float ssq2 = dv.x * dv.x + dv.y * dv.y + dv.z * dv.z + dv.w * dv.w;
        float dot  = p.x * dv.x + p.y * dv.y + p.z * dv.z + p.w * dv.w;
        #pragma unroll
        for (int off = 32; off > 0; off >>= 1) {
            ssq2 += __shfl_down(ssq2, off);
            dot  += __shfl_down(dot, off);
        }
        const float lg = dot / (sqrtf(ssq2) * sqrtf(ssq1) * TEMP);
        logits[k] = __shfl(lg, 0);
    }

    if (lane == 0) {
        float m = logits[0];
        #pragma unroll
        for (int k = 1; k < CATS; ++k) m = fmaxf(m, logits[k]);
        float sum = 0.f;
        #pragma unroll
        for (int k = 0; k < CATS; ++k) sum += expf(logits[k] - m);
        const float lse     = m + logf(sum);
        const int   label   = cs % CATS;
        const float per_row = lse - logits[label];
        if (gCnt[cs] > 0) unsafeAtomicAdd(numAcc, per_row);
    }
}

// ---------------------------------------------------------------------------
// Kernel 3: final scalar division.
// ---------------------------------------------------------------------------
__global__ void finalize_kernel(const int* __restrict__ gCnt,
                                const float* __restrict__ numAcc,
                                float* __restrict__ out) {
    float msum = 0.f;
    for (int i = 0; i < NSEG; ++i) msum += (gCnt[i] > 0) ? 1.f : 0.f;
    out[0] = numAcc[0] / fmaxf(msum, 1.f);
}

extern "C" void kernel_launch(void* const* d_in, const int* in_sizes, int n_in,
                              void* d_out, int out_size, void* d_ws, size_t ws_size,
                              hipStream_t stream) {
    const float* feats  = (const float*)d_in[0];   // [N][256] f32
    const int*   tgt    = (const int*)d_in[1];     // [N] int32
    const int*   lvl    = (const int*)d_in[2];     // [N] int32
    const float* protos = (const float*)d_in[3];   // [17][5][256] f32
    float* out = (float*)d_out;

    const int n = in_sizes[1];                     // N rows

    // ws layout: sums [NSEG*DIM] | numAcc [1] | gCnt [NSEG] | pad | idx [NSEG*n]
    float* sums   = (float*)d_ws;
    float* numAcc = sums + NSEG * DIM;
    int*   gCnt   = (int*)(numAcc + 1);
    const size_t smallBytes = (size_t)(NSEG * DIM + 1 + NSEG) * 4;
    int* idx = (int*)((char*)d_ws + ((smallBytes + 127) & ~(size_t)127));

    hipMemsetAsync(d_ws, 0, smallBytes, stream);

    const int nBuild = (n + CHUNK_ROWS - 1) / CHUNK_ROWS;
    build_kernel<<<nBuild, 256, 0, stream>>>(tgt, lvl, idx, gCnt, n, n);
    gather_kernel<<<NSEG * GPARTS, 256, 0, stream>>>(feats, idx, gCnt, sums, n);
    infonce_kernel<<<NSEG, 64, 0, stream>>>(protos, sums, gCnt, numAcc);
    finalize_kernel<<<1, 1, 0, stream>>>(gCnt, numAcc, out);
}